// Round 1
// baseline (64513.800 us; speedup 1.0000x reference)
//
#include <hip/hip_runtime.h>
#include <math.h>

#define BATCH 4096
#define TSTEPS 512
#define HID 512
#define NCLS 20

typedef __attribute__((ext_vector_type(8))) short short8;
typedef __attribute__((ext_vector_type(4))) float float4v;
typedef unsigned short ushort_t;
typedef unsigned int uint32;

__device__ __forceinline__ float sigmoidf_(float x){ return 1.0f/(1.0f+expf(-x)); }

__device__ __forceinline__ ushort_t f2bf(float f){
  union { float f; uint32 u; } v; v.f = f;
  return (ushort_t)((v.u + 0x7fffu + ((v.u>>16)&1u)) >> 16);
}
__device__ __forceinline__ float bf2f(ushort_t h){
  union { float f; uint32 u; } v; v.u = ((uint32)h)<<16; return v.f;
}

__device__ __forceinline__ void gload16(const void* g, void* l){
  __builtin_amdgcn_global_load_lds(
      (const __attribute__((address_space(1))) uint32*)g,
      (__attribute__((address_space(3))) uint32*)l, 16, 0, 0);
}

// Transpose + hi/lo bf16 split of weight block: W[row0+k][n] -> Wt[n][k], n in [0,2048), k in [0,K)
template<int K>
__global__ __launch_bounds__(256) void prep_w_k(const float* __restrict__ W, int row0,
                                                ushort_t* __restrict__ Whi, ushort_t* __restrict__ Wlo)
{
  __shared__ float s[32][33];
  const int cx = blockIdx.x;   // n tile (64 tiles)
  const int cy = blockIdx.y;   // k tile (K/32 tiles)
  const int tid = threadIdx.x;
  #pragma unroll
  for (int i = 0; i < 4; ++i) {
    int idx = tid + i*256;
    int kk = idx >> 5, nn = idx & 31;
    s[kk][nn] = W[(size_t)(row0 + cy*32 + kk)*2048 + cx*32 + nn];
  }
  __syncthreads();
  #pragma unroll
  for (int i = 0; i < 4; ++i) {
    int idx = tid + i*256;
    int nn = idx >> 5, kk = idx & 31;
    float v = s[kk][nn];
    ushort_t hi = f2bf(v);
    ushort_t lo = f2bf(v - bf2f(hi));
    size_t o = (size_t)(cx*32+nn)*K + cy*32 + kk;
    Whi[o] = hi; Wlo[o] = lo;
  }
}

struct SmemT {
  ushort_t sAhi[128*32];
  ushort_t sAlo[128*32];
  ushort_t sBhi[128*32];
  ushort_t sBlo[128*32];
  float sX[128];
};

// Fused split-bf16 MFMA LSTM step body.
// LDS tiles are stored 16B-quarter-swizzled: LDS[r][q'] holds global (r, q'^((r>>1)&3)).
// Both the store-side and read-side XORs reduce to per-lane constants (zero K-loop cost);
// read pattern then covers all 32 banks exactly 2-way (conflict-free).
template<int KTOT, bool HASX>
__device__ __forceinline__ void lstm_body(
    SmemT& sm,
    const ushort_t* __restrict__ A0hi, const ushort_t* __restrict__ A0lo,
    const ushort_t* __restrict__ A1hi, const ushort_t* __restrict__ A1lo,
    const ushort_t* __restrict__ Bhi,  const ushort_t* __restrict__ Blo,
    const float* __restrict__ bias, const float* __restrict__ wxrow,
    const float* __restrict__ x, int t,
    float* __restrict__ c,
    ushort_t* __restrict__ Hhi, ushort_t* __restrict__ Hlo)
{
  const int tid  = threadIdx.x;
  const int lane = tid & 63;
  const int wave = tid >> 6;      // 0..3
  const int wm   = wave >> 1;     // batch half
  const int wu   = wave & 1;      // unit half
  const int u0   = blockIdx.x * 32;
  const int b0   = blockIdx.y * 128;

  if (HASX) { if (tid < 128) sm.sX[tid] = x[(size_t)(b0 + tid)*TSTEPS + t]; }

  float4v acc[4][4];
  #pragma unroll
  for (int mi = 0; mi < 4; ++mi)
    #pragma unroll
    for (int g = 0; g < 4; ++g) acc[mi][g] = (float4v)0.f;

  const int lrow = lane >> 2;                                   // staged row within 16-row chunk
  const int lq   = ((lane & 3) ^ ((lane >> 3) & 3)) * 8;        // swizzled SOURCE quarter (store side)
  const int qr   = ((lane >> 4) ^ ((lane >> 1) & 3)) * 8;       // swizzled READ quarter

  for (int kt = 0; kt < KTOT; kt += 32) {
    const ushort_t* Ah; const ushort_t* Al; int kk;
    if (KTOT > 512 && kt >= 512) { Ah = A1hi; Al = A1lo; kk = kt - 512; }
    else                         { Ah = A0hi; Al = A0lo; kk = kt; }

    // stage: wave handles rows [wave*32, wave*32+32) of each of the 4 tiles.
    // LDS dest is linear (gload_lds writes base + lane*16B); the swizzle lives in the
    // per-lane global source quarter (lq), same involution as the read side (qr).
    #pragma unroll
    for (int i = 0; i < 2; ++i) {
      const int br = b0 + wave*32 + 16*i + lrow;                 // A global row (batch)
      const int wr = wave*512 + u0 + 16*i + lrow;                // B global row (Wt row = z column)
      gload16(Ah  + (size_t)br*HID  + kk + lq, &sm.sAhi[(wave*32 + 16*i)*32]);
      gload16(Al  + (size_t)br*HID  + kk + lq, &sm.sAlo[(wave*32 + 16*i)*32]);
      gload16(Bhi + (size_t)wr*KTOT + kt + lq, &sm.sBhi[(wave*32 + 16*i)*32]);
      gload16(Blo + (size_t)wr*KTOT + kt + lq, &sm.sBlo[(wave*32 + 16*i)*32]);
    }
    __syncthreads();

    short8 a_hi[4], a_lo[4], b_hi[4], b_lo[4];
    #pragma unroll
    for (int mi = 0; mi < 4; ++mi) {
      int off = (wm*64 + mi*16 + (lane & 15))*32 + qr;
      a_hi[mi] = *(const short8*)&sm.sAhi[off];
      a_lo[mi] = *(const short8*)&sm.sAlo[off];
    }
    #pragma unroll
    for (int g = 0; g < 4; ++g) {
      int off = (g*32 + wu*16 + (lane & 15))*32 + qr;
      b_hi[g] = *(const short8*)&sm.sBhi[off];
      b_lo[g] = *(const short8*)&sm.sBlo[off];
    }
    #pragma unroll
    for (int mi = 0; mi < 4; ++mi)
      #pragma unroll
      for (int g = 0; g < 4; ++g) {
        acc[mi][g] = __builtin_amdgcn_mfma_f32_16x16x32_bf16(a_hi[mi], b_hi[g], acc[mi][g], 0,0,0);
        acc[mi][g] = __builtin_amdgcn_mfma_f32_16x16x32_bf16(a_hi[mi], b_lo[g], acc[mi][g], 0,0,0);
        acc[mi][g] = __builtin_amdgcn_mfma_f32_16x16x32_bf16(a_lo[mi], b_hi[g], acc[mi][g], 0,0,0);
      }
    __syncthreads();
  }

  // epilogue: gates + state update, emit hi/lo bf16 h
  const int ul = u0 + wu*16 + (lane & 15);
  float bb[4], wx[4];
  #pragma unroll
  for (int g = 0; g < 4; ++g) bb[g] = bias[g*512 + ul];
  if (HASX) {
    #pragma unroll
    for (int g = 0; g < 4; ++g) wx[g] = wxrow[g*512 + ul];
  }
  #pragma unroll
  for (int mi = 0; mi < 4; ++mi) {
    #pragma unroll
    for (int r = 0; r < 4; ++r) {
      int b = b0 + wm*64 + mi*16 + (lane >> 4)*4 + r;
      float zi = acc[mi][0][r] + bb[0];
      float zj = acc[mi][1][r] + bb[1];
      float zf = acc[mi][2][r] + bb[2];
      float zo = acc[mi][3][r] + bb[3];
      if (HASX) {
        float xv = sm.sX[b - b0];
        zi += xv*wx[0]; zj += xv*wx[1]; zf += xv*wx[2]; zo += xv*wx[3];
      }
      size_t off = (size_t)b*HID + ul;
      float cv = c[off];
      float cn = cv * sigmoidf_(zf + 1.0f) + sigmoidf_(zi)*tanhf(zj);
      c[off] = cn;
      float hn = tanhf(cn)*sigmoidf_(zo);
      ushort_t hi = f2bf(hn);
      ushort_t lo = f2bf(hn - bf2f(hi));
      Hhi[off] = hi; Hlo[off] = lo;
    }
  }
}

// One launch per timestep computes L2(t) (z=0, dispatched first) and L1(t+1) (z=1)
// concurrently — they are mutually independent (both only READ h1(t)).
// which: 0 = both, 1 = L1 only (prologue), 2 = L2 only (epilogue).
__global__ __launch_bounds__(256) void lstm_fused(
    int which, int t1,
    const ushort_t* __restrict__ a1hi, const ushort_t* __restrict__ a1lo,
    const ushort_t* __restrict__ w1hi, const ushort_t* __restrict__ w1lo,
    const float* __restrict__ b1, const float* __restrict__ w1row, const float* __restrict__ x,
    float* __restrict__ c1, ushort_t* __restrict__ o1hi, ushort_t* __restrict__ o1lo,
    const ushort_t* __restrict__ a2hi, const ushort_t* __restrict__ a2lo,
    const ushort_t* __restrict__ a2bhi, const ushort_t* __restrict__ a2blo,
    const ushort_t* __restrict__ w2hi, const ushort_t* __restrict__ w2lo,
    const float* __restrict__ b2,
    float* __restrict__ c2, ushort_t* __restrict__ o2hi, ushort_t* __restrict__ o2lo)
{
  __shared__ SmemT sm;
  const bool isL1 = (which == 1) || (which == 0 && blockIdx.z == 1);
  if (isL1)
    lstm_body<512,  true >(sm, a1hi, a1lo, nullptr, nullptr, w1hi, w1lo,
                           b1, w1row, x, t1, c1, o1hi, o1lo);
  else
    lstm_body<1024, false>(sm, a2hi, a2lo, a2bhi, a2blo, w2hi, w2lo,
                           b2, nullptr, nullptr, 0, c2, o2hi, o2lo);
}

// Head: logits -> softmax -> argmax. One 64-lane wave per batch row; h2 = hi + lo.
__global__ __launch_bounds__(256) void head_k(
    const ushort_t* __restrict__ h2hi, const ushort_t* __restrict__ h2lo,
    const float* __restrict__ sw, const float* __restrict__ sb, float* __restrict__ out)
{
  int wid  = (blockIdx.x * blockDim.x + threadIdx.x) >> 6;
  int lane = threadIdx.x & 63;
  if (wid >= BATCH) return;
  float acc[NCLS];
  #pragma unroll
  for (int cc = 0; cc < NCLS; ++cc) acc[cc] = 0.f;
  for (int u = lane; u < HID; u += 64) {
    size_t off = (size_t)wid*HID + u;
    float hv = bf2f(h2hi[off]) + bf2f(h2lo[off]);
    #pragma unroll
    for (int cc = 0; cc < NCLS; ++cc) acc[cc] += hv * sw[(size_t)u*NCLS + cc];
  }
  #pragma unroll
  for (int cc = 0; cc < NCLS; ++cc) {
    #pragma unroll
    for (int off = 32; off > 0; off >>= 1) acc[cc] += __shfl_down(acc[cc], off);
  }
  if (lane == 0) {
    float logits[NCLS];
    float mx = -1e30f;
    #pragma unroll
    for (int cc = 0; cc < NCLS; ++cc) { logits[cc] = acc[cc] + sb[cc]; mx = fmaxf(mx, logits[cc]); }
    float ex[NCLS]; float s = 0.f;
    #pragma unroll
    for (int cc = 0; cc < NCLS; ++cc) { ex[cc] = expf(logits[cc] - mx); s += ex[cc]; }
    float inv = 1.f / s;
    int best = 0; float bv = logits[0];
    #pragma unroll
    for (int cc = 1; cc < NCLS; ++cc) { if (logits[cc] > bv) { bv = logits[cc]; best = cc; } }
    float* lo = out;
    float* pr = out + (size_t)BATCH*NCLS;
    float* pc = out + (size_t)2*BATCH*NCLS;
    #pragma unroll
    for (int cc = 0; cc < NCLS; ++cc) {
      lo[(size_t)wid*NCLS + cc] = logits[cc];
      pr[(size_t)wid*NCLS + cc] = ex[cc]*inv;
    }
    pc[wid] = (float)best;
  }
}

extern "C" void kernel_launch(void* const* d_in, const int* in_sizes, int n_in,
                              void* d_out, int out_size, void* d_ws, size_t ws_size,
                              hipStream_t stream) {
  const float* x  = (const float*)d_in[0];
  const float* W1 = (const float*)d_in[1];
  const float* b1 = (const float*)d_in[2];
  const float* W2 = (const float*)d_in[3];
  const float* b2 = (const float*)d_in[4];
  const float* sw = (const float*)d_in[5];
  const float* sb = (const float*)d_in[6];
  float* out = (float*)d_out;

  // workspace layout (elements)
  ushort_t* p = (ushort_t*)d_ws;
  const size_t S = (size_t)BATCH * HID;  // 2M
  ushort_t* W1thi = p;                  p += 2048*512;
  ushort_t* W1tlo = p;                  p += 2048*512;
  ushort_t* W2thi = p;                  p += 2048*1024;
  ushort_t* W2tlo = p;                  p += 2048*1024;
  ushort_t* h1hi[2] = { p, p + S };     p += 2*S;
  ushort_t* h1lo[2] = { p, p + S };     p += 2*S;
  ushort_t* h2hi[2] = { p, p + S };     p += 2*S;
  ushort_t* h2lo[2] = { p, p + S };     p += 2*S;
  float* c1 = (float*)p;
  float* c2 = c1 + S;                   // total = 60 MB

  // one-time (per launch) weight transpose + split
  prep_w_k<512> <<<dim3(64,16), 256, 0, stream>>>(W1, 1, W1thi, W1tlo);
  prep_w_k<1024><<<dim3(64,32), 256, 0, stream>>>(W2, 0, W2thi, W2tlo);

  // convention: h1(t) lives in h1buf[t&1], h2(t) in h2buf[t&1]; h(-1)=0 lives in buf[1]
  hipMemsetAsync(h1hi[1], 0, S*sizeof(ushort_t), stream);
  hipMemsetAsync(h1lo[1], 0, S*sizeof(ushort_t), stream);
  hipMemsetAsync(h2hi[1], 0, S*sizeof(ushort_t), stream);
  hipMemsetAsync(h2lo[1], 0, S*sizeof(ushort_t), stream);
  hipMemsetAsync(c1,      0, S*sizeof(float),    stream);
  hipMemsetAsync(c2,      0, S*sizeof(float),    stream);

  dim3 blk(256);
  dim3 gridBoth(HID/32, BATCH/128, 2);   // 1024 blocks: z=0 -> L2(t), z=1 -> L1(t+1)
  dim3 gridOne (HID/32, BATCH/128, 1);

  // prologue: L1(0) alone (reads h1(-1)=buf[1], writes h1(0)=buf[0])
  lstm_fused<<<gridOne, blk, 0, stream>>>(1, 0,
      h1hi[1], h1lo[1], W1thi, W1tlo, b1, W1, x, c1, h1hi[0], h1lo[0],
      nullptr, nullptr, nullptr, nullptr, W2thi, W2tlo, b2, nullptr, nullptr, nullptr);

  // steady state: launch t computes L2(t) and L1(t+1) concurrently
  for (int t = 0; t < TSTEPS-1; ++t) {
    const int a = t & 1, n = a ^ 1;
    lstm_fused<<<gridBoth, blk, 0, stream>>>(0, t+1,
        h1hi[a], h1lo[a], W1thi, W1tlo, b1, W1, x, c1, h1hi[n], h1lo[n],
        h1hi[a], h1lo[a], h2hi[n], h2lo[n], W2thi, W2tlo, b2, c2, h2hi[a], h2lo[a]);
  }

  // epilogue: L2(511) alone (reads h1(511)=buf[1], h2(510)=buf[0], writes h2(511)=buf[1])
  lstm_fused<<<gridOne, blk, 0, stream>>>(2, 0,
      nullptr, nullptr, W1thi, W1tlo, b1, W1, x, nullptr, nullptr, nullptr,
      h1hi[1], h1lo[1], h2hi[0], h2lo[0], W2thi, W2tlo, b2, c2, h2hi[1], h2lo[1]);

  head_k<<<1024, 256, 0, stream>>>(h2hi[1], h2lo[1], sw, sb, out);
}

// Round 2
// 41061.478 us; speedup vs baseline: 1.5712x; 1.5712x over previous
//
#include <hip/hip_runtime.h>
#include <math.h>

#define BATCH 4096
#define TSTEPS 512
#define HID 512
#define NCLS 20

typedef __attribute__((ext_vector_type(8))) short short8;
typedef __attribute__((ext_vector_type(4))) float float4v;
typedef unsigned short ushort_t;
typedef unsigned int uint32;

__device__ __forceinline__ float sigmoidf_(float x){ return 1.0f/(1.0f+expf(-x)); }

__device__ __forceinline__ ushort_t f2bf(float f){
  union { float f; uint32 u; } v; v.f = f;
  return (ushort_t)((v.u + 0x7fffu + ((v.u>>16)&1u)) >> 16);
}
__device__ __forceinline__ float bf2f(ushort_t h){
  union { float f; uint32 u; } v; v.u = ((uint32)h)<<16; return v.f;
}

__device__ __forceinline__ void gload16(const void* g, void* l){
  __builtin_amdgcn_global_load_lds(
      (const __attribute__((address_space(1))) uint32*)g,
      (__attribute__((address_space(3))) uint32*)l, 16, 0, 0);
}

// Transpose + hi/lo bf16 split of weight block: W[row0+k][n] -> Wt[n][k], n in [0,2048), k in [0,K)
template<int K>
__global__ __launch_bounds__(256) void prep_w_k(const float* __restrict__ W, int row0,
                                                ushort_t* __restrict__ Whi, ushort_t* __restrict__ Wlo)
{
  __shared__ float s[32][33];
  const int cx = blockIdx.x;   // n tile (64 tiles)
  const int cy = blockIdx.y;   // k tile (K/32 tiles)
  const int tid = threadIdx.x;
  #pragma unroll
  for (int i = 0; i < 4; ++i) {
    int idx = tid + i*256;
    int kk = idx >> 5, nn = idx & 31;
    s[kk][nn] = W[(size_t)(row0 + cy*32 + kk)*2048 + cx*32 + nn];
  }
  __syncthreads();
  #pragma unroll
  for (int i = 0; i < 4; ++i) {
    int idx = tid + i*256;
    int nn = idx >> 5, kk = idx & 31;
    float v = s[kk][nn];
    ushort_t hi = f2bf(v);
    ushort_t lo = f2bf(v - bf2f(hi));
    size_t o = (size_t)(cx*32+nn)*K + cy*32 + kk;
    Whi[o] = hi; Wlo[o] = lo;
  }
}

// Fused split-bf16 MFMA LSTM step, BK=64.
// LDS tiles [128][64] bf16 (128B rows). 16B-chunk XOR swizzle (chunk ^= row&7) breaks the
// all-rows-start-at-bank-0 conflict. Store side: gload_lds dest is linear; the swizzle lives
// in the per-lane-constant global source chunk ((lane&7)^(lane>>3)). Read side uses the same
// involution ((ks*4+(lane>>4))^(lane&7)) -> all 32 banks covered 2-way (8-clock minimum).
template<int KTOT, bool HASX>
__global__ __launch_bounds__(256) void lstm_step_mfma(
    const ushort_t* __restrict__ A0hi, const ushort_t* __restrict__ A0lo,
    const ushort_t* __restrict__ A1hi, const ushort_t* __restrict__ A1lo,
    const ushort_t* __restrict__ Bhi,  const ushort_t* __restrict__ Blo,
    const float* __restrict__ bias, const float* __restrict__ wxrow,
    const float* __restrict__ x, int t,
    float* __restrict__ c,
    ushort_t* __restrict__ Hhi, ushort_t* __restrict__ Hlo)
{
  __shared__ ushort_t sAhi[128*64];
  __shared__ ushort_t sAlo[128*64];
  __shared__ ushort_t sBhi[128*64];
  __shared__ ushort_t sBlo[128*64];
  __shared__ float sX[128];

  const int tid  = threadIdx.x;
  const int lane = tid & 63;
  const int wave = tid >> 6;      // 0..3
  const int wm   = wave >> 1;     // batch half
  const int wu   = wave & 1;      // unit half
  const int u0   = blockIdx.x * 32;
  const int b0   = blockIdx.y * 128;

  if (HASX) { if (tid < 128) sX[tid] = x[(size_t)(b0 + tid)*TSTEPS + t]; }

  float4v acc[4][4];
  #pragma unroll
  for (int mi = 0; mi < 4; ++mi)
    #pragma unroll
    for (int g = 0; g < 4; ++g) acc[mi][g] = (float4v)0.f;

  const int srow = lane >> 3;                       // staged row within 8-row chunk (0..7)
  const int sch  = ((lane & 7) ^ (lane >> 3)) * 8;  // swizzled SOURCE chunk offset (elems)

  for (int kt = 0; kt < KTOT; kt += 64) {
    const ushort_t* Ah; const ushort_t* Al; int kk;
    if (KTOT > 512 && kt >= 512) { Ah = A1hi; Al = A1lo; kk = kt - 512; }
    else                         { Ah = A0hi; Al = A0lo; kk = kt; }

    // stage: wave handles rows [wave*32, wave*32+32) of each of the 4 tiles, 8 rows/issue
    #pragma unroll
    for (int i = 0; i < 4; ++i) {
      const int j  = i*8 + srow;                     // row within wave's 32-row slice
      const int br = b0 + wave*32 + j;               // A global row (batch)
      const int wr = wave*512 + u0 + j;              // B global row (Wt row = z column)
      gload16(Ah  + (size_t)br*HID  + kk + sch, &sAhi[(wave*32 + i*8)*64]);
      gload16(Al  + (size_t)br*HID  + kk + sch, &sAlo[(wave*32 + i*8)*64]);
      gload16(Bhi + (size_t)wr*KTOT + kt + sch, &sBhi[(wave*32 + i*8)*64]);
      gload16(Blo + (size_t)wr*KTOT + kt + sch, &sBlo[(wave*32 + i*8)*64]);
    }
    __syncthreads();

    #pragma unroll
    for (int ks = 0; ks < 2; ++ks) {
      const int chR = ((ks*4 + (lane >> 4)) ^ (lane & 7)) * 8;  // swizzled READ chunk (elems)
      short8 a_hi[4], a_lo[4], b_hi[4], b_lo[4];
      #pragma unroll
      for (int mi = 0; mi < 4; ++mi) {
        int off = (wm*64 + mi*16 + (lane & 15))*64 + chR;
        a_hi[mi] = *(const short8*)&sAhi[off];
        a_lo[mi] = *(const short8*)&sAlo[off];
      }
      #pragma unroll
      for (int g = 0; g < 4; ++g) {
        int off = (g*32 + wu*16 + (lane & 15))*64 + chR;
        b_hi[g] = *(const short8*)&sBhi[off];
        b_lo[g] = *(const short8*)&sBlo[off];
      }
      #pragma unroll
      for (int mi = 0; mi < 4; ++mi)
        #pragma unroll
        for (int g = 0; g < 4; ++g) {
          acc[mi][g] = __builtin_amdgcn_mfma_f32_16x16x32_bf16(a_hi[mi], b_hi[g], acc[mi][g], 0,0,0);
          acc[mi][g] = __builtin_amdgcn_mfma_f32_16x16x32_bf16(a_hi[mi], b_lo[g], acc[mi][g], 0,0,0);
          acc[mi][g] = __builtin_amdgcn_mfma_f32_16x16x32_bf16(a_lo[mi], b_hi[g], acc[mi][g], 0,0,0);
        }
    }
    __syncthreads();
  }

  // epilogue: gates + state update, emit hi/lo bf16 h
  const int ul = u0 + wu*16 + (lane & 15);
  float bb[4], wx[4];
  #pragma unroll
  for (int g = 0; g < 4; ++g) bb[g] = bias[g*512 + ul];
  if (HASX) {
    #pragma unroll
    for (int g = 0; g < 4; ++g) wx[g] = wxrow[g*512 + ul];
  }
  #pragma unroll
  for (int mi = 0; mi < 4; ++mi) {
    #pragma unroll
    for (int r = 0; r < 4; ++r) {
      int b = b0 + wm*64 + mi*16 + (lane >> 4)*4 + r;
      float zi = acc[mi][0][r] + bb[0];
      float zj = acc[mi][1][r] + bb[1];
      float zf = acc[mi][2][r] + bb[2];
      float zo = acc[mi][3][r] + bb[3];
      if (HASX) {
        float xv = sX[b - b0];
        zi += xv*wx[0]; zj += xv*wx[1]; zf += xv*wx[2]; zo += xv*wx[3];
      }
      size_t off = (size_t)b*HID + ul;
      float cv = c[off];
      float cn = cv * sigmoidf_(zf + 1.0f) + sigmoidf_(zi)*tanhf(zj);
      c[off] = cn;
      float hn = tanhf(cn)*sigmoidf_(zo);
      ushort_t hi = f2bf(hn);
      ushort_t lo = f2bf(hn - bf2f(hi));
      Hhi[off] = hi; Hlo[off] = lo;
    }
  }
}

// Head: logits -> softmax -> argmax. One 64-lane wave per batch row; h2 = hi + lo.
__global__ __launch_bounds__(256) void head_k(
    const ushort_t* __restrict__ h2hi, const ushort_t* __restrict__ h2lo,
    const float* __restrict__ sw, const float* __restrict__ sb, float* __restrict__ out)
{
  int wid  = (blockIdx.x * blockDim.x + threadIdx.x) >> 6;
  int lane = threadIdx.x & 63;
  if (wid >= BATCH) return;
  float acc[NCLS];
  #pragma unroll
  for (int cc = 0; cc < NCLS; ++cc) acc[cc] = 0.f;
  for (int u = lane; u < HID; u += 64) {
    size_t off = (size_t)wid*HID + u;
    float hv = bf2f(h2hi[off]) + bf2f(h2lo[off]);
    #pragma unroll
    for (int cc = 0; cc < NCLS; ++cc) acc[cc] += hv * sw[(size_t)u*NCLS + cc];
  }
  #pragma unroll
  for (int cc = 0; cc < NCLS; ++cc) {
    #pragma unroll
    for (int off = 32; off > 0; off >>= 1) acc[cc] += __shfl_down(acc[cc], off);
  }
  if (lane == 0) {
    float logits[NCLS];
    float mx = -1e30f;
    #pragma unroll
    for (int cc = 0; cc < NCLS; ++cc) { logits[cc] = acc[cc] + sb[cc]; mx = fmaxf(mx, logits[cc]); }
    float ex[NCLS]; float s = 0.f;
    #pragma unroll
    for (int cc = 0; cc < NCLS; ++cc) { ex[cc] = expf(logits[cc] - mx); s += ex[cc]; }
    float inv = 1.f / s;
    int best = 0; float bv = logits[0];
    #pragma unroll
    for (int cc = 1; cc < NCLS; ++cc) { if (logits[cc] > bv) { bv = logits[cc]; best = cc; } }
    float* lo = out;
    float* pr = out + (size_t)BATCH*NCLS;
    float* pc = out + (size_t)2*BATCH*NCLS;
    #pragma unroll
    for (int cc = 0; cc < NCLS; ++cc) {
      lo[(size_t)wid*NCLS + cc] = logits[cc];
      pr[(size_t)wid*NCLS + cc] = ex[cc]*inv;
    }
    pc[wid] = (float)best;
  }
}

extern "C" void kernel_launch(void* const* d_in, const int* in_sizes, int n_in,
                              void* d_out, int out_size, void* d_ws, size_t ws_size,
                              hipStream_t stream) {
  const float* x  = (const float*)d_in[0];
  const float* W1 = (const float*)d_in[1];
  const float* b1 = (const float*)d_in[2];
  const float* W2 = (const float*)d_in[3];
  const float* b2 = (const float*)d_in[4];
  const float* sw = (const float*)d_in[5];
  const float* sb = (const float*)d_in[6];
  float* out = (float*)d_out;

  // workspace layout (elements)
  ushort_t* p = (ushort_t*)d_ws;
  const size_t S = (size_t)BATCH * HID;  // 2M
  ushort_t* W1thi = p;                  p += 2048*512;
  ushort_t* W1tlo = p;                  p += 2048*512;
  ushort_t* W2thi = p;                  p += 2048*1024;
  ushort_t* W2tlo = p;                  p += 2048*1024;
  ushort_t* h1hi[2] = { p, p + S };     p += 2*S;
  ushort_t* h1lo[2] = { p, p + S };     p += 2*S;
  ushort_t* h2hi[2] = { p, p + S };     p += 2*S;
  ushort_t* h2lo[2] = { p, p + S };     p += 2*S;
  float* c1 = (float*)p;
  float* c2 = c1 + S;                   // total = 60 MB

  // one-time (per launch) weight transpose + split
  prep_w_k<512> <<<dim3(64,16), 256, 0, stream>>>(W1, 1, W1thi, W1tlo);
  prep_w_k<1024><<<dim3(64,32), 256, 0, stream>>>(W2, 0, W2thi, W2tlo);

  hipMemsetAsync(h1hi[0], 0, S*sizeof(ushort_t), stream);
  hipMemsetAsync(h1lo[0], 0, S*sizeof(ushort_t), stream);
  hipMemsetAsync(h2hi[0], 0, S*sizeof(ushort_t), stream);
  hipMemsetAsync(h2lo[0], 0, S*sizeof(ushort_t), stream);
  hipMemsetAsync(c1,      0, S*sizeof(float),    stream);
  hipMemsetAsync(c2,      0, S*sizeof(float),    stream);

  dim3 grid(HID/32, BATCH/128);   // 16 x 32 = 512 blocks
  for (int t = 0; t < TSTEPS; ++t) {
    int cur = t & 1, nxt = cur ^ 1;
    lstm_step_mfma<512,  true ><<<grid, 256, 0, stream>>>(
        h1hi[cur], h1lo[cur], nullptr, nullptr,
        W1thi, W1tlo, b1, W1 /*row 0 = x weights*/, x, t,
        c1, h1hi[nxt], h1lo[nxt]);
    lstm_step_mfma<1024, false><<<grid, 256, 0, stream>>>(
        h1hi[nxt], h1lo[nxt], h2hi[cur], h2lo[cur],
        W2thi, W2tlo, b2, nullptr, nullptr, 0,
        c2, h2hi[nxt], h2lo[nxt]);
  }
  // final h2 written at t=511 -> buffer 0
  head_k<<<1024, 256, 0, stream>>>(h2hi[0], h2lo[0], sw, sb, out);
}